// Round 9
// baseline (988.943 us; speedup 1.0000x reference)
//
#include <hip/hip_runtime.h>
#include <stdint.h>

// MixBlock3D: B=2 C=256 D=8 H=56 W=56, GWS=(2,7,7). I/O f32, intermediates bf16.
// Round 16: conv wave decomposition flipped to 32 tok x 64 oc (halves per-wave
// A-tile LDS reads: 16 -> 8 ds_read_b128 per tap) and B software-pipelined one
// kk-step ahead (bnext loaded before bcur's MFMAs, crossing the tap barrier).
// Rest identical to round 15 (803.3 us measured).

typedef unsigned short u16;
typedef __attribute__((ext_vector_type(8))) short short8;  // 8 bf16 = 4 VGPR
typedef __attribute__((ext_vector_type(4))) float f32x4;   // 4 fp32 acc

#define TOK   50176
#define CH    256
#define SPAT  25088
#define PLANE 3136

__device__ __forceinline__ float b2f(u16 u) {
    union { uint32_t i; float f; } v; v.i = ((uint32_t)u) << 16; return v.f;
}
__device__ __forceinline__ u16 f2b(float f) {
    union { float f; uint32_t i; } v; v.f = f;
    uint32_t i = v.i;
    uint32_t r = i + 0x7FFFu + ((i >> 16) & 1u);
    return (u16)(r >> 16);
}

// ---------------- weight f32 -> bf16 copy (row-major preserved) -------------
__global__ __launch_bounds__(256) void cvtw_kernel(
    const float* __restrict__ src, u16* __restrict__ dst)
{
    int i = (blockIdx.x * 256 + threadIdx.x) * 4;
    float4 v = *(const float4*)(src + i);
    ushort4 p;
    p.x = f2b(v.x); p.y = f2b(v.y); p.z = f2b(v.z); p.w = f2b(v.w);
    *(ushort4*)(dst + i) = p;
}

// ---------------- LN1: NCDHW f32 -> token-major (t, c) bf16 -----------------
__global__ __launch_bounds__(256) void ln1_kernel(
    const float* __restrict__ x, const float* __restrict__ w,
    const float* __restrict__ bsh, u16* __restrict__ out)
{
    int t = blockIdx.x * 256 + threadIdx.x;
    int b = t / SPAT, sp = t % SPAT;
    const float* px = x + (size_t)b * CH * SPAT + sp;
    float s = 0.f, ss = 0.f;
    for (int c = 0; c < CH; c++) { float v = px[(size_t)c * SPAT]; s += v; ss += v * v; }
    float mean = s * (1.0f / CH);
    float var  = ss * (1.0f / CH) - mean * mean;
    float rstd = rsqrtf(var + 1e-5f);
    u16* po = out + (size_t)t * CH;
    for (int c = 0; c < CH; c++) {
        float v = (px[(size_t)c * SPAT] - mean) * rstd * w[c] + bsh[c];
        po[c] = f2b(v);
    }
}

// ---------------- LN2: token-major bf16 -> token-major bf16 -----------------
__global__ __launch_bounds__(256) void ln2_kernel(
    const u16* __restrict__ x, const float* __restrict__ w,
    const float* __restrict__ bsh, u16* __restrict__ out)
{
    int wave = threadIdx.x >> 6, lane = threadIdx.x & 63;
    int t = blockIdx.x * 4 + wave;
    const u16* px = x + (size_t)t * CH + lane * 4;
    ushort4 v4 = *(const ushort4*)px;
    float v0 = b2f(v4.x), v1 = b2f(v4.y), v2 = b2f(v4.z), v3 = b2f(v4.w);
    float s = v0 + v1 + v2 + v3;
    float ss = v0*v0 + v1*v1 + v2*v2 + v3*v3;
    for (int o = 32; o > 0; o >>= 1) {
        s  += __shfl_xor(s,  o, 64);
        ss += __shfl_xor(ss, o, 64);
    }
    float mean = s * (1.0f / CH);
    float rstd = rsqrtf(ss * (1.0f / CH) - mean * mean + 1e-5f);
    float4 w4 = *(const float4*)(w + lane * 4);
    float4 b4 = *(const float4*)(bsh + lane * 4);
    ushort4 o4;
    o4.x = f2b((v0 - mean) * rstd * w4.x + b4.x);
    o4.y = f2b((v1 - mean) * rstd * w4.y + b4.y);
    o4.z = f2b((v2 - mean) * rstd * w4.z + b4.z);
    o4.w = f2b((v3 - mean) * rstd * w4.w + b4.w);
    *(ushort4*)(out + (size_t)t * CH + lane * 4) = o4;
}

// ---- MFMA GEMM: C[M,Nout slice] = A[M,256](bf16) @ B[N,256]^T(bf16 weights) --
__global__ __launch_bounds__(256) void gemm_mfma_kernel(
    const u16* __restrict__ A, const u16* __restrict__ B,
    const float* __restrict__ bias, const u16* __restrict__ res,
    u16* __restrict__ C, int Nout)
{
    __shared__ u16 sAg[128][72];
    __shared__ u16 sBg[128][72];
    int tid = threadIdx.x;
    int m0 = blockIdx.x * 128, n0g = blockIdx.y * 128;
    int lane = tid & 63, wv = tid >> 6;
    int quad = lane >> 4, l15 = lane & 15;
    int mw = (wv & 1) * 64, nw = (wv >> 1) * 64;

    f32x4 zz = {0.f, 0.f, 0.f, 0.f};
    f32x4 acc[4][4];
    #pragma unroll
    for (int i = 0; i < 4; i++)
        #pragma unroll
        for (int j = 0; j < 4; j++) acc[i][j] = zz;

    for (int kc = 0; kc < 256; kc += 64) {
        __syncthreads();
        #pragma unroll
        for (int i = 0; i < 4; i++) {
            int unit = tid + i * 256;
            int row = unit >> 3, k8 = (unit & 7) << 3;
            *(uint4*)&sAg[row][k8] = *(const uint4*)(A + (size_t)(m0 + row) * 256 + kc + k8);
        }
        #pragma unroll
        for (int i = 0; i < 4; i++) {
            int unit = tid + i * 256;
            int row = unit >> 3, k8 = (unit & 7) << 3;
            *(uint4*)&sBg[row][k8] = *(const uint4*)(B + (size_t)(n0g + row) * 256 + kc + k8);
        }
        __syncthreads();
        #pragma unroll
        for (int kk = 0; kk < 2; kk++) {
            short8 afr[4], bfr[4];
            #pragma unroll
            for (int mt = 0; mt < 4; mt++)
                afr[mt] = *(const short8*)&sAg[mw + mt*16 + l15][kk*32 + quad*8];
            #pragma unroll
            for (int nt = 0; nt < 4; nt++)
                bfr[nt] = *(const short8*)&sBg[nw + nt*16 + l15][kk*32 + quad*8];
            #pragma unroll
            for (int mt = 0; mt < 4; mt++)
                #pragma unroll
                for (int nt = 0; nt < 4; nt++)
                    acc[mt][nt] = __builtin_amdgcn_mfma_f32_16x16x32_bf16(
                        afr[mt], bfr[nt], acc[mt][nt], 0, 0, 0);
        }
    }

    #pragma unroll
    for (int nt = 0; nt < 4; nt++) {
        int n = n0g + nw + nt*16 + l15;
        float bv = bias ? bias[n] : 0.f;
        #pragma unroll
        for (int mt = 0; mt < 4; mt++) {
            int m = m0 + mw + mt*16 + quad*4;
            #pragma unroll
            for (int r = 0; r < 4; r++) {
                float v = acc[mt][nt][r] + bv;
                size_t off = (size_t)(m + r) * Nout + n;
                if (res) v += b2f(res[off]);
                C[off] = f2b(v);
            }
        }
    }
}

// ---------------- MFMA Attention: one block per (group, head) ---------------
__global__ __launch_bounds__(256) void attn_mfma_kernel(
    const u16* __restrict__ qkv, const float* __restrict__ btab,
    u16* __restrict__ outp, int mode)
{
    __shared__ u16 sKV[8704];        // K [112][72] then V^T [64][136]
    __shared__ u16 sS[112][136];
    __shared__ float sBias[507];
    __shared__ int sTok[112];
    __shared__ int sEnc[112];
    __shared__ float sInv[112];

    int g = blockIdx.x, head = blockIdx.y, tid = threadIdx.x;
    int b  = g >> 8;
    int gd = (g >> 6) & 3, gh = (g >> 3) & 7, gw = g & 7;

    int lane = tid & 63, wv = tid >> 6;
    int quad = lane >> 4, l15 = lane & 15;
    int mts[2] = {wv, wv + 4};

    if (tid < 112) {
        int t = tid;
        int i = t / 49, r = t % 49, j = r / 7, k = r % 7;
        sEnc[tid] = i * 169 + j * 13 + k;
        int tokv = 0;
        if (t < 98) {
            int d, h, w;
            if (mode == 0) { d = gd*2 + i; h = gh*7 + j; w = gw*7 + k; }
            else           { d = i*4 + gd; h = j*8 + gh; w = k*8 + gw; }
            tokv = ((b*8 + d)*56 + h)*56 + w;
        }
        sTok[tid] = tokv;
    }
    for (int idx = tid; idx < 507; idx += 256) sBias[idx] = btab[idx * 4 + head];
    __syncthreads();

    for (int idx = tid; idx < 112 * 8; idx += 256) {
        int row = idx >> 3, c8 = (idx & 7) << 3;
        uint4 v = {0u, 0u, 0u, 0u};
        if (row < 98)
            v = *(const uint4*)(qkv + (size_t)sTok[row] * 768 + 256 + head * 64 + c8);
        *(uint4*)&sKV[row * 72 + c8] = v;
    }
    __syncthreads();

    short8 qf[2][2];
    #pragma unroll
    for (int mi = 0; mi < 2; mi++) {
        int mt = mts[mi];
        #pragma unroll
        for (int ks = 0; ks < 2; ks++) {
            short8 v;
            #pragma unroll
            for (int j = 0; j < 8; j++) v[j] = 0;
            int row = mt * 16 + l15;
            if (mt < 7 && row < 98)
                v = *(const short8*)(qkv + (size_t)sTok[row] * 768 + head * 64 + ks * 32 + quad * 8);
            qf[mi][ks] = v;
        }
    }

    f32x4 zz = {0.f, 0.f, 0.f, 0.f};
    #pragma unroll
    for (int mi = 0; mi < 2; mi++) {
        int mt = mts[mi];
        if (mt >= 7) continue;
        for (int nt = 0; nt < 7; nt++) {
            f32x4 acc = zz;
            acc = __builtin_amdgcn_mfma_f32_16x16x32_bf16(
                qf[mi][0], *(const short8*)&sKV[(nt*16 + l15) * 72 + quad*8], acc, 0, 0, 0);
            acc = __builtin_amdgcn_mfma_f32_16x16x32_bf16(
                qf[mi][1], *(const short8*)&sKV[(nt*16 + l15) * 72 + 32 + quad*8], acc, 0, 0, 0);
            int n = nt * 16 + l15;
            int en = (n < 98) ? sEnc[n] : 0;
            #pragma unroll
            for (int r = 0; r < 4; r++) {
                int m = mt * 16 + quad * 4 + r;
                float v;
                if (n < 98) {
                    int em = sEnc[m < 98 ? m : 97];
                    v = acc[r] * 0.125f + sBias[em - en + 253];
                } else v = -1e30f;
                sS[m][n] = f2b(v);
            }
        }
    }
    __syncthreads();

    for (int idx = tid; idx < 64 * 30; idx += 256) {
        int c = idx / 30, t = 98 + idx % 30;
        sKV[c * 136 + t] = 0;
    }
    for (int idx = tid; idx < 98 * 8; idx += 256) {
        int tok = idx >> 3, c8 = (idx & 7) << 3;
        uint4 v = *(const uint4*)(qkv + (size_t)sTok[tok] * 768 + 512 + head * 64 + c8);
        const u16* pv = (const u16*)&v;
        #pragma unroll
        for (int j = 0; j < 8; j++) sKV[(c8 + j) * 136 + tok] = pv[j];
    }

    {
        int row = tid >> 1, half = tid & 1;
        if (row < 112) {
            #pragma unroll
            for (int j = 0; j < 8; j++) sS[row][112 + half * 8 + j] = 0;
        }
        if (row < 98) {
            int c0 = half * 49;
            float mx = -1e30f;
            for (int j = 0; j < 49; j++) mx = fmaxf(mx, b2f(sS[row][c0 + j]));
            mx = fmaxf(mx, __shfl_xor(mx, 1, 64));
            float sum = 0.f;
            for (int j = 0; j < 49; j++) {
                float e = __expf(b2f(sS[row][c0 + j]) - mx);
                sum += e;
                sS[row][c0 + j] = f2b(e);
            }
            sum += __shfl_xor(sum, 1, 64);
            if (half == 0) sInv[row] = 1.0f / sum;
        }
    }
    __syncthreads();

    f32x4 po[2][4];
    #pragma unroll
    for (int mi = 0; mi < 2; mi++)
        #pragma unroll
        for (int nt = 0; nt < 4; nt++) po[mi][nt] = zz;

    #pragma unroll
    for (int mi = 0; mi < 2; mi++) {
        int mt = mts[mi];
        if (mt >= 7) continue;
        for (int ks = 0; ks < 4; ks++) {
            short8 ap = *(const short8*)&sS[mt*16 + l15][ks*32 + quad*8];
            #pragma unroll
            for (int nt = 0; nt < 4; nt++) {
                short8 bv = *(const short8*)&sKV[(nt*16 + l15) * 136 + ks*32 + quad*8];
                po[mi][nt] = __builtin_amdgcn_mfma_f32_16x16x32_bf16(ap, bv, po[mi][nt], 0, 0, 0);
            }
        }
    }

    #pragma unroll
    for (int mi = 0; mi < 2; mi++) {
        int mt = mts[mi];
        if (mt >= 7) continue;
        #pragma unroll
        for (int r = 0; r < 4; r++) {
            int m = mt * 16 + quad * 4 + r;
            if (m >= 98) continue;
            float inv = sInv[m];
            u16* dst = outp + (size_t)sTok[m] * 256 + head * 64 + l15;
            #pragma unroll
            for (int nt = 0; nt < 4; nt++)
                dst[nt * 16] = f2b(po[mi][nt][r] * inv);
        }
    }
}

// ---- s = input(f32 NCDHW) + y(bf16 token-major) -> s1/s2 channel-last bf16 --
__global__ __launch_bounds__(256) void ssplit_cl_kernel(
    const float* __restrict__ inp, const u16* __restrict__ y,
    u16* __restrict__ s1, u16* __restrict__ s2)
{
    __shared__ float sT[64][65];
    int t0 = blockIdx.x * 64;
    int b = t0 / SPAT, sp0 = t0 % SPAT;
    int tid = threadIdx.x;
    for (int cg = 0; cg < 4; cg++) {
        __syncthreads();
        #pragma unroll
        for (int i = 0; i < 16; i++) {
            int unit = tid + i * 256;
            int cl = unit >> 6, spl = unit & 63;
            sT[spl][cl] = inp[((size_t)(b * 256 + cg * 64 + cl)) * SPAT + sp0 + spl];
        }
        __syncthreads();
        int spl = tid >> 2, c16 = (tid & 3) * 16;
        int tok = t0 + spl;
        const u16* yp = y + (size_t)tok * 256 + cg * 64 + c16;
        int cbase = cg * 64 + c16;
        u16* dst = (cbase < 128) ? (s1 + (size_t)tok * 128 + cbase)
                                 : (s2 + (size_t)tok * 128 + cbase - 128);
        #pragma unroll
        for (int j = 0; j < 16; j++) {
            float v = sT[spl][c16 + j] + b2f(yp[j]);
            dst[j] = f2b(v);
        }
    }
}

// ---- conv weight transform: f32 [oc][ic][27] -> bf16 fragment-linear -------
__global__ __launch_bounds__(256) void convw_kernel(
    const float* __restrict__ w, u16* __restrict__ o)
{
    int e = blockIdx.x * 256 + threadIdx.x;   // 442368 total
    int tap = e >> 14;
    int r = e & 16383;
    int kk = r >> 12;
    int nt = (r >> 9) & 7;
    int quad = (r >> 7) & 3;
    int l15 = (r >> 3) & 15;
    int j = r & 7;
    int oc = nt * 16 + l15;
    int ic = kk * 32 + quad * 8 + j;
    o[e] = f2b(w[(size_t)(oc * 128 + ic) * 27 + tap]);
}

// ---- MFMA conv 3x3x3 128->128: 32tok x 64oc waves + kk-pipelined B ---------
// block: 64 tokens x 128 oc, 4 waves. wave = 32 tok (tokgrp=wv&1) x 64 oc
// (och=wv>>1): 8 ds_read_b128/tap (half of r15) + 16 B loads/tap pipelined
// one kk-step ahead (bnext issued before bcur's MFMAs, crossing the barrier).
__global__ __launch_bounds__(256, 3) void conv_mfma_kernel(
    const u16* __restrict__ in_cl,   // [B*SPAT][128] bf16
    const u16* __restrict__ wtf,     // fragment-linear weights (442368)
    const float* __restrict__ bias,  // [128] f32
    const u16* __restrict__ res_cl,  // nullable [tok][128] bf16 (added to acc)
    u16* __restrict__ out_cl,        // nullable [tok][128] bf16
    float* __restrict__ out_f32,     // nullable NCDHW f32 (256-ch layout)
    int oc_base, int leaky)
{
    __shared__ u16 sA[2][8192];      // 32,768 B (aliased as f32 sT in epilogue)

    int tid = threadIdx.x;
    int t0 = blockIdx.x * 64;
    int b = t0 / SPAT, sp0 = t0 % SPAT;

    int lane = tid & 63, wv = tid >> 6;
    int quad = lane >> 4, l15 = lane & 15;
    int tokgrp = wv & 1, och = wv >> 1;
    int ntb = och * 4;               // B fragment row base (ntIdx = ntb + nt)

    // staging geometry (unchanged, tid-based)
    int ms  = wv * 16 + l15;
    int sp  = sp0 + ms;
    int d_s = sp / PLANE; int rr_ = sp % PLANE;
    int h_s = rr_ / 56, w_s = rr_ % 56;
    int lin_s = t0 + ms;
    const int icb = quad * 8;

    f32x4 zz = {0.f, 0.f, 0.f, 0.f};
    f32x4 acc[2][4];
    #pragma unroll
    for (int i = 0; i < 2; i++)
        #pragma unroll
        for (int j = 0; j < 4; j++) acc[i][j] = zz;

    uint4 pre[4];

    #define STAGE_REGS(TAP)                                                    \
    {                                                                          \
        const int kd = (TAP) / 9 - 1, kh = ((TAP) / 3) % 3 - 1,                \
                  kw = (TAP) % 3 - 1;                                          \
        int dd = d_s + kd, hh = h_s + kh, ww = w_s + kw;                       \
        bool ok = ((unsigned)dd < 8u) & ((unsigned)hh < 56u) &                 \
                  ((unsigned)ww < 56u);                                        \
        const u16* src = in_cl +                                               \
            (size_t)(lin_s + kd * PLANE + kh * 56 + kw) * 128 + icb;           \
        _Pragma("unroll")                                                      \
        for (int i = 0; i < 4; i++) {                                          \
            uint4 v = {0u, 0u, 0u, 0u};                                        \
            if (ok) v = *(const uint4*)(src + i * 32);                         \
            pre[i] = v;                                                        \
        }                                                                      \
    }

    #define LOADB(DST, TAP, KK)                                                \
    {                                                                          \
        const u16* wp_ = wtf + (size_t)(TAP) * 16384;                          \
        _Pragma("unroll")                                                      \
        for (int nt_ = 0; nt_ < 4; nt_++)                                      \
            DST[nt_] = *(const short8*)(wp_ +                                  \
                (((KK) * 8 + ntb + nt_) * 64 + lane) * 8);                     \
    }

    STAGE_REGS(0);
    #pragma unroll
    for (int i = 0; i < 4; i++) *(uint4*)&sA[0][(tid + i * 256) * 8] = pre[i];
    __syncthreads();

    short8 bcur[4], bnext[4];
    LOADB(bcur, 0, 0);

    for (int tap = 0; tap < 27; tap++) {
        int cur = tap & 1;
        if (tap < 26) STAGE_REGS(tap + 1);

        #pragma unroll
        for (int kk = 0; kk < 4; kk++) {
            // prefetch next kk's (or next tap's kk=0) B fragments
            if (kk < 3) {
                LOADB(bnext, tap, kk + 1);
            } else if (tap < 26) {
                LOADB(bnext, tap + 1, 0);
            }
            short8 afr[2];
            #pragma unroll
            for (int mi = 0; mi < 2; mi++) {
                int mt = tokgrp * 2 + mi;
                afr[mi] = *(const short8*)&sA[cur][((kk*4 + mt)*64 + lane) * 8];
            }
            #pragma unroll
            for (int mi = 0; mi < 2; mi++)
                #pragma unroll
                for (int nt = 0; nt < 4; nt++)
                    acc[mi][nt] = __builtin_amdgcn_mfma_f32_16x16x32_bf16(
                        afr[mi], bcur[nt], acc[mi][nt], 0, 0, 0);
            #pragma unroll
            for (int nt = 0; nt < 4; nt++) bcur[nt] = bnext[nt];
        }

        if (tap < 26) {
            #pragma unroll
            for (int i = 0; i < 4; i++)
                *(uint4*)&sA[cur ^ 1][(tid + i * 256) * 8] = pre[i];
        }
        __syncthreads();
    }
    #undef STAGE_REGS
    #undef LOADB

    // bias + leaky + residual (into ACC so both outputs get it)
    #pragma unroll
    for (int nt = 0; nt < 4; nt++) {
        int oc = och * 64 + nt*16 + l15;
        float bv = bias[oc];
        #pragma unroll
        for (int mi = 0; mi < 2; mi++) {
            int m = (tokgrp*2 + mi)*16 + quad*4;
            #pragma unroll
            for (int r = 0; r < 4; r++) {
                float v = acc[mi][nt][r] + bv;
                if (leaky) v = (v >= 0.f) ? v : 0.01f * v;
                if (res_cl) v += b2f(res_cl[(size_t)(t0 + m + r) * 128 + oc]);
                acc[mi][nt][r] = v;
            }
        }
    }

    if (out_cl) {
        #pragma unroll
        for (int mi = 0; mi < 2; mi++) {
            int m = (tokgrp*2 + mi)*16 + quad*4;
            #pragma unroll
            for (int nt = 0; nt < 4; nt++) {
                int oc = och * 64 + nt*16 + l15;
                #pragma unroll
                for (int r = 0; r < 4; r++)
                    out_cl[(size_t)(t0 + m + r) * 128 + oc] = f2b(acc[mi][nt][r]);
            }
        }
    }

    if (out_f32) {
        __syncthreads();
        float* sT = (float*)&sA[0][0];   // [128][64] f32 = 32,768 B
        #pragma unroll
        for (int mi = 0; mi < 2; mi++) {
            int m = (tokgrp*2 + mi)*16 + quad*4;
            #pragma unroll
            for (int nt = 0; nt < 4; nt++) {
                int oc = och * 64 + nt*16 + l15;
                #pragma unroll
                for (int r = 0; r < 4; r++)
                    sT[oc * 64 + ((m + r + oc) & 63)] = acc[mi][nt][r];  // skewed
            }
        }
        __syncthreads();
        int oc = tid >> 1, half = tid & 1;
        size_t obase = ((size_t)b * 256 + oc_base + oc) * SPAT + sp0 + half * 32;
        const float* row = &sT[oc * 64];
        for (int j = 0; j < 32; j++) {
            int m = half * 32 + j;
            out_f32[obase + j] = row[(m + oc) & 63];   // unskew
        }
    }
}

// ---------------- launch ----------------------------------------------------
extern "C" void kernel_launch(void* const* d_in, const int* in_sizes, int n_in,
                              void* d_out, int out_size, void* d_ws, size_t ws_size,
                              hipStream_t stream)
{
    const float* input  = (const float*)d_in[0];
    const float* n1w    = (const float*)d_in[1];
    const float* n1b    = (const float*)d_in[2];
    const float* n2w    = (const float*)d_in[3];
    const float* n2b    = (const float*)d_in[4];
    const float* wqkv   = (const float*)d_in[5];
    const float* wprojw = (const float*)d_in[6];
    const float* wprojb = (const float*)d_in[7];
    const float* wbias  = (const float*)d_in[8];
    const float* gqkv   = (const float*)d_in[9];
    const float* gprojw = (const float*)d_in[10];
    const float* gprojb = (const float*)d_in[11];
    const float* gbias  = (const float*)d_in[12];
    const float* f1c1w  = (const float*)d_in[13];
    const float* f1c1b  = (const float*)d_in[14];
    const float* f1c2w  = (const float*)d_in[15];
    const float* f1c2b  = (const float*)d_in[16];
    const float* g1c1w  = (const float*)d_in[17];
    const float* g1c1b  = (const float*)d_in[18];
    const float* g1c2w  = (const float*)d_in[19];
    const float* g1c2b  = (const float*)d_in[20];

    char* ws = (char*)d_ws;
    u16* xln   = (u16*)(ws);                    // 25,690,112 B (later: y)
    u16* qkv   = (u16*)(ws + 25690112);         // 77,070,336 B (later: conv bufs)
    u16* attnb = (u16*)(ws + 102760448);        // 25,690,112 B
    u16* xw    = (u16*)(ws + 128450560);        // 25,690,112 B
    u16* y  = xln;
    u16* s1   = qkv;
    u16* s2   = (u16*)(ws + 25690112 + 12845056);
    u16* tb   = (u16*)(ws + 25690112 + 25690112);
    u16* y1cl = (u16*)(ws + 25690112 + 38535168);
    u16* cw0  = (u16*)(ws + 25690112 + 51380224);
    u16* cw1  = cw0 + 442368;
    u16* cw2  = cw1 + 442368;
    u16* cw3  = cw2 + 442368;

    float* outp = (float*)d_out;

    // bf16 GEMM weights live in d_out scratch (dead until step 12; steps 12/14
    // overwrite ALL of d_out afterwards)
    u16* wqkvB  = (u16*)d_out;                  // 768*256
    u16* gqkvB  = wqkvB + 196608;               // 768*256
    u16* wprojB = gqkvB + 196608;               // 256*256
    u16* gprojB = wprojB + 65536;               // 256*256

    // 0) weight conversions (once)
    cvtw_kernel<<<192, 256, 0, stream>>>(wqkv,   wqkvB);
    cvtw_kernel<<<192, 256, 0, stream>>>(gqkv,   gqkvB);
    cvtw_kernel<<<64,  256, 0, stream>>>(wprojw, wprojB);
    cvtw_kernel<<<64,  256, 0, stream>>>(gprojw, gprojB);
    // 1) LN1
    ln1_kernel<<<196, 256, 0, stream>>>(input, n1w, n1b, xln);
    // 2) window qkv
    gemm_mfma_kernel<<<dim3(392, 6), 256, 0, stream>>>(xln, wqkvB, nullptr, nullptr, qkv, 768);
    // 3) window attention (MFMA)
    attn_mfma_kernel<<<dim3(512, 4), 256, 0, stream>>>(qkv, wbias, attnb, 0);
    // 4) window proj -> xw
    gemm_mfma_kernel<<<dim3(392, 2), 256, 0, stream>>>(attnb, wprojB, wprojb, nullptr, xw, 256);
    // 5) LN2 -> xln
    ln2_kernel<<<12544, 256, 0, stream>>>(xw, n2w, n2b, xln);
    // 6) grid qkv
    gemm_mfma_kernel<<<dim3(392, 6), 256, 0, stream>>>(xln, gqkvB, nullptr, nullptr, qkv, 768);
    // 7) grid attention (MFMA)
    attn_mfma_kernel<<<dim3(512, 4), 256, 0, stream>>>(qkv, gbias, attnb, 1);
    // 8) grid proj + xw residual -> y
    gemm_mfma_kernel<<<dim3(392, 2), 256, 0, stream>>>(attnb, gprojB, gprojb, xw, y, 256);
    // 9) s = input + y -> channel-last halves
    ssplit_cl_kernel<<<784, 256, 0, stream>>>(input, y, s1, s2);
    // 10) conv weight transforms (fragment-linear)
    convw_kernel<<<1728, 256, 0, stream>>>(f1c1w, cw0);
    convw_kernel<<<1728, 256, 0, stream>>>(f1c2w, cw1);
    convw_kernel<<<1728, 256, 0, stream>>>(g1c1w, cw2);
    convw_kernel<<<1728, 256, 0, stream>>>(g1c2w, cw3);
    // 11) t = leaky(conv(s2, f1c1))
    conv_mfma_kernel<<<784, 256, 0, stream>>>(s2, cw0, f1c1b, nullptr, tb, nullptr, 0, 1);
    // 12) y1 = s1 + conv(t, f1c2) -> d_out[:,0:128] and y1cl
    conv_mfma_kernel<<<784, 256, 0, stream>>>(tb, cw1, f1c2b, s1, y1cl, outp, 0, 0);
    // 13) t = leaky(conv(y1, g1c1))
    conv_mfma_kernel<<<784, 256, 0, stream>>>(y1cl, cw2, g1c1b, nullptr, tb, nullptr, 0, 1);
    // 14) y2 = s2 + conv(t, g1c2) -> d_out[:,128:256]
    conv_mfma_kernel<<<784, 256, 0, stream>>>(tb, cw3, g1c2b, s2, nullptr, outp, 128, 0);
}

// Round 10
// 796.599 us; speedup vs baseline: 1.2415x; 1.2415x over previous
//
#include <hip/hip_runtime.h>
#include <stdint.h>

// MixBlock3D: B=2 C=256 D=8 H=56 W=56, GWS=(2,7,7). I/O f32, intermediates bf16.
// Round 17: conv reverted to the measured-best r15 form (95.4us: per-tap
// staging, 64tok x 32oc waves, tap-hoisted B cluster). Attention softmax
// rewritten wave-parallel: row max/sum via in-lane nt-reduce + 16-lane
// shfl_xor on the QK^T accumulators; normalized bf16 P stored directly;
// serial 49-iter softmax block and final 1/sum multiply removed.

typedef unsigned short u16;
typedef __attribute__((ext_vector_type(8))) short short8;  // 8 bf16 = 4 VGPR
typedef __attribute__((ext_vector_type(4))) float f32x4;   // 4 fp32 acc

#define TOK   50176
#define CH    256
#define SPAT  25088
#define PLANE 3136

__device__ __forceinline__ float b2f(u16 u) {
    union { uint32_t i; float f; } v; v.i = ((uint32_t)u) << 16; return v.f;
}
__device__ __forceinline__ u16 f2b(float f) {
    union { float f; uint32_t i; } v; v.f = f;
    uint32_t i = v.i;
    uint32_t r = i + 0x7FFFu + ((i >> 16) & 1u);
    return (u16)(r >> 16);
}

// ---------------- weight f32 -> bf16 copy (row-major preserved) -------------
__global__ __launch_bounds__(256) void cvtw_kernel(
    const float* __restrict__ src, u16* __restrict__ dst)
{
    int i = (blockIdx.x * 256 + threadIdx.x) * 4;
    float4 v = *(const float4*)(src + i);
    ushort4 p;
    p.x = f2b(v.x); p.y = f2b(v.y); p.z = f2b(v.z); p.w = f2b(v.w);
    *(ushort4*)(dst + i) = p;
}

// ---------------- LN1: NCDHW f32 -> token-major (t, c) bf16 -----------------
__global__ __launch_bounds__(256) void ln1_kernel(
    const float* __restrict__ x, const float* __restrict__ w,
    const float* __restrict__ bsh, u16* __restrict__ out)
{
    int t = blockIdx.x * 256 + threadIdx.x;
    int b = t / SPAT, sp = t % SPAT;
    const float* px = x + (size_t)b * CH * SPAT + sp;
    float s = 0.f, ss = 0.f;
    for (int c = 0; c < CH; c++) { float v = px[(size_t)c * SPAT]; s += v; ss += v * v; }
    float mean = s * (1.0f / CH);
    float var  = ss * (1.0f / CH) - mean * mean;
    float rstd = rsqrtf(var + 1e-5f);
    u16* po = out + (size_t)t * CH;
    for (int c = 0; c < CH; c++) {
        float v = (px[(size_t)c * SPAT] - mean) * rstd * w[c] + bsh[c];
        po[c] = f2b(v);
    }
}

// ---------------- LN2: token-major bf16 -> token-major bf16 -----------------
__global__ __launch_bounds__(256) void ln2_kernel(
    const u16* __restrict__ x, const float* __restrict__ w,
    const float* __restrict__ bsh, u16* __restrict__ out)
{
    int wave = threadIdx.x >> 6, lane = threadIdx.x & 63;
    int t = blockIdx.x * 4 + wave;
    const u16* px = x + (size_t)t * CH + lane * 4;
    ushort4 v4 = *(const ushort4*)px;
    float v0 = b2f(v4.x), v1 = b2f(v4.y), v2 = b2f(v4.z), v3 = b2f(v4.w);
    float s = v0 + v1 + v2 + v3;
    float ss = v0*v0 + v1*v1 + v2*v2 + v3*v3;
    for (int o = 32; o > 0; o >>= 1) {
        s  += __shfl_xor(s,  o, 64);
        ss += __shfl_xor(ss, o, 64);
    }
    float mean = s * (1.0f / CH);
    float rstd = rsqrtf(ss * (1.0f / CH) - mean * mean + 1e-5f);
    float4 w4 = *(const float4*)(w + lane * 4);
    float4 b4 = *(const float4*)(bsh + lane * 4);
    ushort4 o4;
    o4.x = f2b((v0 - mean) * rstd * w4.x + b4.x);
    o4.y = f2b((v1 - mean) * rstd * w4.y + b4.y);
    o4.z = f2b((v2 - mean) * rstd * w4.z + b4.z);
    o4.w = f2b((v3 - mean) * rstd * w4.w + b4.w);
    *(ushort4*)(out + (size_t)t * CH + lane * 4) = o4;
}

// ---- MFMA GEMM: C[M,Nout slice] = A[M,256](bf16) @ B[N,256]^T(bf16 weights) --
__global__ __launch_bounds__(256) void gemm_mfma_kernel(
    const u16* __restrict__ A, const u16* __restrict__ B,
    const float* __restrict__ bias, const u16* __restrict__ res,
    u16* __restrict__ C, int Nout)
{
    __shared__ u16 sAg[128][72];
    __shared__ u16 sBg[128][72];
    int tid = threadIdx.x;
    int m0 = blockIdx.x * 128, n0g = blockIdx.y * 128;
    int lane = tid & 63, wv = tid >> 6;
    int quad = lane >> 4, l15 = lane & 15;
    int mw = (wv & 1) * 64, nw = (wv >> 1) * 64;

    f32x4 zz = {0.f, 0.f, 0.f, 0.f};
    f32x4 acc[4][4];
    #pragma unroll
    for (int i = 0; i < 4; i++)
        #pragma unroll
        for (int j = 0; j < 4; j++) acc[i][j] = zz;

    for (int kc = 0; kc < 256; kc += 64) {
        __syncthreads();
        #pragma unroll
        for (int i = 0; i < 4; i++) {
            int unit = tid + i * 256;
            int row = unit >> 3, k8 = (unit & 7) << 3;
            *(uint4*)&sAg[row][k8] = *(const uint4*)(A + (size_t)(m0 + row) * 256 + kc + k8);
        }
        #pragma unroll
        for (int i = 0; i < 4; i++) {
            int unit = tid + i * 256;
            int row = unit >> 3, k8 = (unit & 7) << 3;
            *(uint4*)&sBg[row][k8] = *(const uint4*)(B + (size_t)(n0g + row) * 256 + kc + k8);
        }
        __syncthreads();
        #pragma unroll
        for (int kk = 0; kk < 2; kk++) {
            short8 afr[4], bfr[4];
            #pragma unroll
            for (int mt = 0; mt < 4; mt++)
                afr[mt] = *(const short8*)&sAg[mw + mt*16 + l15][kk*32 + quad*8];
            #pragma unroll
            for (int nt = 0; nt < 4; nt++)
                bfr[nt] = *(const short8*)&sBg[nw + nt*16 + l15][kk*32 + quad*8];
            #pragma unroll
            for (int mt = 0; mt < 4; mt++)
                #pragma unroll
                for (int nt = 0; nt < 4; nt++)
                    acc[mt][nt] = __builtin_amdgcn_mfma_f32_16x16x32_bf16(
                        afr[mt], bfr[nt], acc[mt][nt], 0, 0, 0);
        }
    }

    #pragma unroll
    for (int nt = 0; nt < 4; nt++) {
        int n = n0g + nw + nt*16 + l15;
        float bv = bias ? bias[n] : 0.f;
        #pragma unroll
        for (int mt = 0; mt < 4; mt++) {
            int m = m0 + mw + mt*16 + quad*4;
            #pragma unroll
            for (int r = 0; r < 4; r++) {
                float v = acc[mt][nt][r] + bv;
                size_t off = (size_t)(m + r) * Nout + n;
                if (res) v += b2f(res[off]);
                C[off] = f2b(v);
            }
        }
    }
}

// ---------------- MFMA Attention: one block per (group, head) ---------------
// Softmax fused into the QK^T epilogue, wave-parallel: row lives across the
// 16-lane l15 group (7 nt values in-register); max/sum = in-lane reduce +
// shfl_xor(1,2,4,8). Normalized bf16 P stored; no serial phase, no sInv.
__global__ __launch_bounds__(256) void attn_mfma_kernel(
    const u16* __restrict__ qkv, const float* __restrict__ btab,
    u16* __restrict__ outp, int mode)
{
    __shared__ u16 sKV[8704];        // K [112][72] then V^T [64][136]
    __shared__ u16 sS[112][136];
    __shared__ float sBias[507];
    __shared__ int sTok[112];
    __shared__ int sEnc[112];

    int g = blockIdx.x, head = blockIdx.y, tid = threadIdx.x;
    int b  = g >> 8;
    int gd = (g >> 6) & 3, gh = (g >> 3) & 7, gw = g & 7;

    int lane = tid & 63, wv = tid >> 6;
    int quad = lane >> 4, l15 = lane & 15;
    int mts[2] = {wv, wv + 4};

    if (tid < 112) {
        int t = tid;
        int i = t / 49, r = t % 49, j = r / 7, k = r % 7;
        sEnc[tid] = i * 169 + j * 13 + k;
        int tokv = 0;
        if (t < 98) {
            int d, h, w;
            if (mode == 0) { d = gd*2 + i; h = gh*7 + j; w = gw*7 + k; }
            else           { d = i*4 + gd; h = j*8 + gh; w = k*8 + gw; }
            tokv = ((b*8 + d)*56 + h)*56 + w;
        }
        sTok[tid] = tokv;
    }
    for (int idx = tid; idx < 507; idx += 256) sBias[idx] = btab[idx * 4 + head];
    __syncthreads();

    for (int idx = tid; idx < 112 * 8; idx += 256) {
        int row = idx >> 3, c8 = (idx & 7) << 3;
        uint4 v = {0u, 0u, 0u, 0u};
        if (row < 98)
            v = *(const uint4*)(qkv + (size_t)sTok[row] * 768 + 256 + head * 64 + c8);
        *(uint4*)&sKV[row * 72 + c8] = v;
    }
    __syncthreads();

    short8 qf[2][2];
    #pragma unroll
    for (int mi = 0; mi < 2; mi++) {
        int mt = mts[mi];
        #pragma unroll
        for (int ks = 0; ks < 2; ks++) {
            short8 v;
            #pragma unroll
            for (int j = 0; j < 8; j++) v[j] = 0;
            int row = mt * 16 + l15;
            if (mt < 7 && row < 98)
                v = *(const short8*)(qkv + (size_t)sTok[row] * 768 + head * 64 + ks * 32 + quad * 8);
            qf[mi][ks] = v;
        }
    }

    // per-lane column encodings (col n = nt*16 + l15, always < 112)
    int enc_n[7];
    #pragma unroll
    for (int nt = 0; nt < 7; nt++) enc_n[nt] = sEnc[nt * 16 + l15];
    bool ncut = (l15 >= 2);          // nt==6 && l15>=2  <=>  n >= 98

    f32x4 zz = {0.f, 0.f, 0.f, 0.f};
    #pragma unroll
    for (int mi = 0; mi < 2; mi++) {
        int mt = mts[mi];
        if (mt >= 7) continue;
        f32x4 sc[7];
        for (int nt = 0; nt < 7; nt++) {
            f32x4 a = zz;
            a = __builtin_amdgcn_mfma_f32_16x16x32_bf16(
                qf[mi][0], *(const short8*)&sKV[(nt*16 + l15) * 72 + quad*8], a, 0, 0, 0);
            a = __builtin_amdgcn_mfma_f32_16x16x32_bf16(
                qf[mi][1], *(const short8*)&sKV[(nt*16 + l15) * 72 + 32 + quad*8], a, 0, 0, 0);
            sc[nt] = a;
        }
        #pragma unroll
        for (int r = 0; r < 4; r++) {
            int m = mt * 16 + quad * 4 + r;
            int em = sEnc[m < 98 ? m : 97];
            float v[7];
            #pragma unroll
            for (int nt = 0; nt < 7; nt++) {
                float s = sc[nt][r] * 0.125f + sBias[em - enc_n[nt] + 253];
                if (nt == 6 && ncut) s = -1e30f;
                v[nt] = s;
            }
            float mx = v[0];
            #pragma unroll
            for (int nt = 1; nt < 7; nt++) mx = fmaxf(mx, v[nt]);
            #pragma unroll
            for (int o = 1; o < 16; o <<= 1) mx = fmaxf(mx, __shfl_xor(mx, o, 64));
            float e[7], sum = 0.f;
            #pragma unroll
            for (int nt = 0; nt < 7; nt++) {
                float ev = (nt == 6 && ncut) ? 0.f : __expf(v[nt] - mx);
                e[nt] = ev; sum += ev;
            }
            #pragma unroll
            for (int o = 1; o < 16; o <<= 1) sum += __shfl_xor(sum, o, 64);
            float inv = 1.0f / sum;
            #pragma unroll
            for (int nt = 0; nt < 7; nt++)
                sS[m][nt*16 + l15] = f2b(e[nt] * inv);
            sS[m][112 + l15] = 0;    // zero-pad cols 112..127 for PV ks=3
        }
    }
    __syncthreads();

    for (int idx = tid; idx < 64 * 30; idx += 256) {
        int c = idx / 30, t = 98 + idx % 30;
        sKV[c * 136 + t] = 0;
    }
    for (int idx = tid; idx < 98 * 8; idx += 256) {
        int tok = idx >> 3, c8 = (idx & 7) << 3;
        uint4 v = *(const uint4*)(qkv + (size_t)sTok[tok] * 768 + 512 + head * 64 + c8);
        const u16* pv = (const u16*)&v;
        #pragma unroll
        for (int j = 0; j < 8; j++) sKV[(c8 + j) * 136 + tok] = pv[j];
    }
    __syncthreads();

    f32x4 po[2][4];
    #pragma unroll
    for (int mi = 0; mi < 2; mi++)
        #pragma unroll
        for (int nt = 0; nt < 4; nt++) po[mi][nt] = zz;

    #pragma unroll
    for (int mi = 0; mi < 2; mi++) {
        int mt = mts[mi];
        if (mt >= 7) continue;
        for (int ks = 0; ks < 4; ks++) {
            short8 ap = *(const short8*)&sS[mt*16 + l15][ks*32 + quad*8];
            #pragma unroll
            for (int nt = 0; nt < 4; nt++) {
                short8 bv = *(const short8*)&sKV[(nt*16 + l15) * 136 + ks*32 + quad*8];
                po[mi][nt] = __builtin_amdgcn_mfma_f32_16x16x32_bf16(ap, bv, po[mi][nt], 0, 0, 0);
            }
        }
    }

    #pragma unroll
    for (int mi = 0; mi < 2; mi++) {
        int mt = mts[mi];
        if (mt >= 7) continue;
        #pragma unroll
        for (int r = 0; r < 4; r++) {
            int m = mt * 16 + quad * 4 + r;
            if (m >= 98) continue;
            u16* dst = outp + (size_t)sTok[m] * 256 + head * 64 + l15;
            #pragma unroll
            for (int nt = 0; nt < 4; nt++)
                dst[nt * 16] = f2b(po[mi][nt][r]);
        }
    }
}

// ---- s = input(f32 NCDHW) + y(bf16 token-major) -> s1/s2 channel-last bf16 --
__global__ __launch_bounds__(256) void ssplit_cl_kernel(
    const float* __restrict__ inp, const u16* __restrict__ y,
    u16* __restrict__ s1, u16* __restrict__ s2)
{
    __shared__ float sT[64][65];
    int t0 = blockIdx.x * 64;
    int b = t0 / SPAT, sp0 = t0 % SPAT;
    int tid = threadIdx.x;
    for (int cg = 0; cg < 4; cg++) {
        __syncthreads();
        #pragma unroll
        for (int i = 0; i < 16; i++) {
            int unit = tid + i * 256;
            int cl = unit >> 6, spl = unit & 63;
            sT[spl][cl] = inp[((size_t)(b * 256 + cg * 64 + cl)) * SPAT + sp0 + spl];
        }
        __syncthreads();
        int spl = tid >> 2, c16 = (tid & 3) * 16;
        int tok = t0 + spl;
        const u16* yp = y + (size_t)tok * 256 + cg * 64 + c16;
        int cbase = cg * 64 + c16;
        u16* dst = (cbase < 128) ? (s1 + (size_t)tok * 128 + cbase)
                                 : (s2 + (size_t)tok * 128 + cbase - 128);
        #pragma unroll
        for (int j = 0; j < 16; j++) {
            float v = sT[spl][c16 + j] + b2f(yp[j]);
            dst[j] = f2b(v);
        }
    }
}

// ---- conv weight transform: f32 [oc][ic][27] -> bf16 fragment-linear -------
__global__ __launch_bounds__(256) void convw_kernel(
    const float* __restrict__ w, u16* __restrict__ o)
{
    int e = blockIdx.x * 256 + threadIdx.x;   // 442368 total
    int tap = e >> 14;
    int r = e & 16383;
    int kk = r >> 12;
    int nt = (r >> 9) & 7;
    int quad = (r >> 7) & 3;
    int l15 = (r >> 3) & 15;
    int j = r & 7;
    int oc = nt * 16 + l15;
    int ic = kk * 32 + quad * 8 + j;
    o[e] = f2b(w[(size_t)(oc * 128 + ic) * 27 + tap]);
}

// ---- MFMA conv 3x3x3 128->128: r15 structure (measured 95.4us) -------------
__global__ __launch_bounds__(256, 4) void conv_mfma_kernel(
    const u16* __restrict__ in_cl,   // [B*SPAT][128] bf16
    const u16* __restrict__ wtf,     // fragment-linear weights (442368)
    const float* __restrict__ bias,  // [128] f32
    const u16* __restrict__ res_cl,  // nullable [tok][128] bf16 (added to acc)
    u16* __restrict__ out_cl,        // nullable [tok][128] bf16
    float* __restrict__ out_f32,     // nullable NCDHW f32 (256-ch layout)
    int oc_base, int leaky)
{
    __shared__ u16 sA[2][8192];      // 32,768 B (aliased as f32 sT in epilogue)

    int tid = threadIdx.x;
    int t0 = blockIdx.x * 64;
    int b = t0 / SPAT, sp0 = t0 % SPAT;

    int lane = tid & 63, wv = tid >> 6;
    int quad = lane >> 4, l15 = lane & 15;
    int n0 = wv * 32;
    int nbase = wv * 2;              // n0/16

    int ms  = wv * 16 + l15;
    int sp  = sp0 + ms;
    int d_s = sp / PLANE; int rr_ = sp % PLANE;
    int h_s = rr_ / 56, w_s = rr_ % 56;
    int lin_s = t0 + ms;
    const int icb = quad * 8;

    f32x4 zz = {0.f, 0.f, 0.f, 0.f};
    f32x4 acc[4][2];
    #pragma unroll
    for (int i = 0; i < 4; i++) { acc[i][0] = zz; acc[i][1] = zz; }

    uint4 pre[4];

    #define STAGE_REGS(TAP)                                                    \
    {                                                                          \
        const int kd = (TAP) / 9 - 1, kh = ((TAP) / 3) % 3 - 1,                \
                  kw = (TAP) % 3 - 1;                                          \
        int dd = d_s + kd, hh = h_s + kh, ww = w_s + kw;                       \
        bool ok = ((unsigned)dd < 8u) & ((unsigned)hh < 56u) &                 \
                  ((unsigned)ww < 56u);                                        \
        const u16* src = in_cl +                                               \
            (size_t)(lin_s + kd * PLANE + kh * 56 + kw) * 128 + icb;           \
        _Pragma("unroll")                                                      \
        for (int i = 0; i < 4; i++) {                                          \
            uint4 v = {0u, 0u, 0u, 0u};                                        \
            if (ok) v = *(const uint4*)(src + i * 32);                         \
            pre[i] = v;                                                        \
        }                                                                      \
    }

    STAGE_REGS(0);
    #pragma unroll
    for (int i = 0; i < 4; i++) *(uint4*)&sA[0][(tid + i * 256) * 8] = pre[i];
    __syncthreads();

    for (int tap = 0; tap < 27; tap++) {
        int cur = tap & 1;

        // B fragments for THIS tap: one 8-load cluster issued first so the
        // L2 latency overlaps the ds_reads + leading MFMAs below.
        const u16* wb = wtf + tap * 16384;
        short8 bfr[4][2];
        #pragma unroll
        for (int kk = 0; kk < 4; kk++)
            #pragma unroll
            for (int nt = 0; nt < 2; nt++)
                bfr[kk][nt] = *(const short8*)(wb + ((kk*8 + nbase + nt)*64 + lane) * 8);

        if (tap < 26) STAGE_REGS(tap + 1);

        #pragma unroll
        for (int kk = 0; kk < 4; kk++) {
            short8 afr[4];
            #pragma unroll
            for (int mt = 0; mt < 4; mt++)
                afr[mt] = *(const short8*)&sA[cur][((kk*4 + mt)*64 + lane) * 8];
            #pragma unroll
            for (int mt = 0; mt < 4; mt++)
                #pragma unroll
                for (int nt = 0; nt < 2; nt++)
                    acc[mt][nt] = __builtin_amdgcn_mfma_f32_16x16x32_bf16(
                        afr[mt], bfr[kk][nt], acc[mt][nt], 0, 0, 0);
        }

        if (tap < 26) {
            #pragma unroll
            for (int i = 0; i < 4; i++)
                *(uint4*)&sA[cur ^ 1][(tid + i * 256) * 8] = pre[i];
        }
        __syncthreads();
    }
    #undef STAGE_REGS

    #pragma unroll
    for (int nt = 0; nt < 2; nt++) {
        int oc = n0 + nt*16 + l15;
        float bv = bias[oc];
        #pragma unroll
        for (int mt = 0; mt < 4; mt++) {
            int m = mt*16 + quad*4;
            #pragma unroll
            for (int r = 0; r < 4; r++) {
                float v = acc[mt][nt][r] + bv;
                if (leaky) v = (v >= 0.f) ? v : 0.01f * v;
                if (res_cl) v += b2f(res_cl[(size_t)(t0 + m + r) * 128 + oc]);
                acc[mt][nt][r] = v;
            }
        }
    }

    if (out_cl) {
        #pragma unroll
        for (int mt = 0; mt < 4; mt++) {
            int m = mt*16 + quad*4;
            #pragma unroll
            for (int nt = 0; nt < 2; nt++) {
                int oc = n0 + nt*16 + l15;
                #pragma unroll
                for (int r = 0; r < 4; r++)
                    out_cl[(size_t)(t0 + m + r) * 128 + oc] = f2b(acc[mt][nt][r]);
            }
        }
    }

    if (out_f32) {
        __syncthreads();
        float* sT = (float*)&sA[0][0];   // [128][64] f32 = 32,768 B
        #pragma unroll
        for (int mt = 0; mt < 4; mt++) {
            int m = mt*16 + quad*4;
            #pragma unroll
            for (int nt = 0; nt < 2; nt++) {
                int oc = n0 + nt*16 + l15;
                #pragma unroll
                for (int r = 0; r < 4; r++)
                    sT[oc * 64 + ((m + r + oc) & 63)] = acc[mt][nt][r];  // skewed
            }
        }
        __syncthreads();
        int oc = tid >> 1, half = tid & 1;
        size_t obase = ((size_t)b * 256 + oc_base + oc) * SPAT + sp0 + half * 32;
        const float* row = &sT[oc * 64];
        for (int j = 0; j < 32; j++) {
            int m = half * 32 + j;
            out_f32[obase + j] = row[(m + oc) & 63];   // unskew
        }
    }
}

// ---------------- launch ----------------------------------------------------
extern "C" void kernel_launch(void* const* d_in, const int* in_sizes, int n_in,
                              void* d_out, int out_size, void* d_ws, size_t ws_size,
                              hipStream_t stream)
{
    const float* input  = (const float*)d_in[0];
    const float* n1w    = (const float*)d_in[1];
    const float* n1b    = (const float*)d_in[2];
    const float* n2w    = (const float*)d_in[3];
    const float* n2b    = (const float*)d_in[4];
    const float* wqkv   = (const float*)d_in[5];
    const float* wprojw = (const float*)d_in[6];
    const float* wprojb = (const float*)d_in[7];
    const float* wbias  = (const float*)d_in[8];
    const float* gqkv   = (const float*)d_in[9];
    const float* gprojw = (const float*)d_in[10];
    const float* gprojb = (const float*)d_in[11];
    const float* gbias  = (const float*)d_in[12];
    const float* f1c1w  = (const float*)d_in[13];
    const float* f1c1b  = (const float*)d_in[14];
    const float* f1c2w  = (const float*)d_in[15];
    const float* f1c2b  = (const float*)d_in[16];
    const float* g1c1w  = (const float*)d_in[17];
    const float* g1c1b  = (const float*)d_in[18];
    const float* g1c2w  = (const float*)d_in[19];
    const float* g1c2b  = (const float*)d_in[20];

    char* ws = (char*)d_ws;
    u16* xln   = (u16*)(ws);                    // 25,690,112 B (later: y)
    u16* qkv   = (u16*)(ws + 25690112);         // 77,070,336 B (later: conv bufs)
    u16* attnb = (u16*)(ws + 102760448);        // 25,690,112 B
    u16* xw    = (u16*)(ws + 128450560);        // 25,690,112 B
    u16* y  = xln;
    u16* s1   = qkv;
    u16* s2   = (u16*)(ws + 25690112 + 12845056);
    u16* tb   = (u16*)(ws + 25690112 + 25690112);
    u16* y1cl = (u16*)(ws + 25690112 + 38535168);
    u16* cw0  = (u16*)(ws + 25690112 + 51380224);
    u16* cw1  = cw0 + 442368;
    u16* cw2  = cw1 + 442368;
    u16* cw3  = cw2 + 442368;

    float* outp = (float*)d_out;

    // bf16 GEMM weights live in d_out scratch (dead until step 12; steps 12/14
    // overwrite ALL of d_out afterwards)
    u16* wqkvB  = (u16*)d_out;                  // 768*256
    u16* gqkvB  = wqkvB + 196608;               // 768*256
    u16* wprojB = gqkvB + 196608;               // 256*256
    u16* gprojB = wprojB + 65536;               // 256*256

    // 0) weight conversions (once)
    cvtw_kernel<<<192, 256, 0, stream>>>(wqkv,   wqkvB);
    cvtw_kernel<<<192, 256, 0, stream>>>(gqkv,   gqkvB);
    cvtw_kernel<<<64,  256, 0, stream>>>(wprojw, wprojB);
    cvtw_kernel<<<64,  256, 0, stream>>>(gprojw, gprojB);
    // 1) LN1
    ln1_kernel<<<196, 256, 0, stream>>>(input, n1w, n1b, xln);
    // 2) window qkv
    gemm_mfma_kernel<<<dim3(392, 6), 256, 0, stream>>>(xln, wqkvB, nullptr, nullptr, qkv, 768);
    // 3) window attention (MFMA)
    attn_mfma_kernel<<<dim3(512, 4), 256, 0, stream>>>(qkv, wbias, attnb, 0);
    // 4) window proj -> xw
    gemm_mfma_kernel<<<dim3(392, 2), 256, 0, stream>>>(attnb, wprojB, wprojb, nullptr, xw, 256);
    // 5) LN2 -> xln
    ln2_kernel<<<12544, 256, 0, stream>>>(xw, n2w, n2b, xln);
    // 6) grid qkv
    gemm_mfma_kernel<<<dim3(392, 6), 256, 0, stream>>>(xln, gqkvB, nullptr, nullptr, qkv, 768);
    // 7) grid attention (MFMA)
    attn_mfma_kernel<<<dim3(512, 4), 256, 0, stream>>>(qkv, gbias, attnb, 1);
    // 8) grid proj + xw residual -> y
    gemm_mfma_kernel<<<dim3(392, 2), 256, 0, stream>>>(attnb, gprojB, gprojb, xw, y, 256);
    // 9) s = input + y -> channel-last halves
    ssplit_cl_kernel<<<784, 256, 0, stream>>>(input, y, s1, s2);
    // 10) conv weight transforms (fragment-linear)
    convw_kernel<<<1728, 256, 0, stream>>>(f1c1w, cw0);
    convw_kernel<<<1728, 256, 0, stream>>>(f1c2w, cw1);
    convw_kernel<<<1728, 256, 0, stream>>>(g1c1w, cw2);
    convw_kernel<<<1728, 256, 0, stream>>>(g1c2w, cw3);
    // 11) t = leaky(conv(s2, f1c1))
    conv_mfma_kernel<<<784, 256, 0, stream>>>(s2, cw0, f1c1b, nullptr, tb, nullptr, 0, 1);
    // 12) y1 = s1 + conv(t, f1c2) -> d_out[:,0:128] and y1cl
    conv_mfma_kernel<<<784, 256, 0, stream>>>(tb, cw1, f1c2b, s1, y1cl, outp, 0, 0);
    // 13) t = leaky(conv(y1, g1c1))
    conv_mfma_kernel<<<784, 256, 0, stream>>>(y1cl, cw2, g1c1b, nullptr, tb, nullptr, 0, 1);
    // 14) y2 = s2 + conv(t, g1c2) -> d_out[:,128:256]
    conv_mfma_kernel<<<784, 256, 0, stream>>>(tb, cw3, g1c2b, s2, nullptr, outp, 128, 0);
}